// Round 17
// baseline (1156.345 us; speedup 1.0000x reference)
//
#include <hip/hip_runtime.h>
#include <hip/hip_fp16.h>
#include <math.h>

#define TT 256
#define HC 128
#define HB 64
#define NL 8

// ---- ws layout ----
// uint view [0, 65536): packed fp16 weights, 8192 per layer:
//   [L*8192 + c*32 + o2]       = (W[c][2o2], W[c][2o2+1])   u-phase, pk_fma layout
//   [L*8192 + 4096 + c*32 + k] = (Po[c][2k], Po[c][2k+1])   s-phase (Po = pw_out)
// float view: Pb @65536, Pg @66048, Gp @66560, Bp @67584
#define WS_PB  65536
#define WS_PG  66048
#define WS_GP  66560
#define WS_BP  67584

typedef _Float16 h2vec __attribute__((ext_vector_type(2)));

__device__ __forceinline__ float fdot2(unsigned a, unsigned b, float c) {
#if __has_builtin(__builtin_amdgcn_fdot2)
    return __builtin_amdgcn_fdot2(__builtin_bit_cast(h2vec, a),
                                  __builtin_bit_cast(h2vec, b), c, false);
#else
    __half2 ah = __builtin_bit_cast(__half2, a);
    __half2 bh = __builtin_bit_cast(__half2, b);
    c = fmaf(__low2float(ah), __low2float(bh), c);
    return fmaf(__high2float(ah), __high2float(bh), c);
#endif
}

__device__ __forceinline__ float fast_tanh(float x) {
    float e = __expf(2.f * fabsf(x));
    float r = 1.f - 2.f / (1.f + e);
    return copysignf(r, x);
}
__device__ __forceinline__ float fast_sig(float x) {
    return 1.f / (1.f + __expf(-x));
}
__device__ __forceinline__ unsigned packh2(float a, float b) {
    __half2 h = __floats2half2_rn(a, b);
    return __builtin_bit_cast(unsigned, h);
}
__device__ __forceinline__ float loh(unsigned u) {
    return __low2float(__builtin_bit_cast(__half2, u));
}
__device__ __forceinline__ float hih(unsigned u) {
    return __high2float(__builtin_bit_cast(__half2, u));
}

__global__ __launch_bounds__(256)
void tcn_setup(const float* __restrict__ pw_in, const float* __restrict__ pw_out,
               const float* __restrict__ gn_g, const float* __restrict__ gn_b,
               float* __restrict__ ws) {
    const int i = blockIdx.x;      // layer
    const int tid = threadIdx.x;   // 256 threads
    unsigned* WP = (unsigned*)ws;
    float* Pb = ws + WS_PB;
    float* Pg = ws + WS_PG;
    float* Gp = ws + WS_GP;
    float* Bp = ws + WS_BP;

    if (tid < HC) {
        float g  = (i == 0) ? 1.f : gn_g[(i - 1) * HC + tid];
        float bb = (i == 0) ? 0.f : gn_b[(i - 1) * HC + tid];
        Gp[i * HC + tid] = g;
        Bp[i * HC + tid] = bb;
    }
    // u-phase weights (pk_fma layout): Wu[c*32+o2] = (pw_in[i][2o2][c]*g[c], pw_in[i][2o2+1][c]*g[c])
    for (int e = tid; e < 4096; e += 256) {
        int c = e >> 5, o2 = e & 31;
        float g = (i == 0) ? 1.f : gn_g[(i - 1) * HC + c];
        float w0 = pw_in[((size_t)i * HB + 2 * o2) * HC + c] * g;
        float w1 = pw_in[((size_t)i * HB + 2 * o2 + 1) * HC + c] * g;
        WP[(size_t)i * 8192 + e] = packh2(w0, w1);
    }
    // s-phase weights: Pp[c*32+k] = (pw_out[i][c][2k], pw_out[i][c][2k+1])
    for (int e = tid; e < 4096; e += 256) {
        int c = e >> 5, k = e & 31;
        float w0 = pw_out[((size_t)i * HC + c) * HB + 2 * k];
        float w1 = pw_out[((size_t)i * HC + c) * HB + 2 * k + 1];
        WP[(size_t)i * 8192 + 4096 + e] = packh2(w0, w1);
    }
    if (tid < HB) {
        float pb = 0.f, pg = 0.f;
        for (int c = 0; c < HC; c++) {
            float w = pw_in[((size_t)i * HB + tid) * HC + c];
            float gc = (i == 0) ? 1.f : gn_g[(i - 1) * HC + c];
            float bc = (i == 0) ? 0.f : gn_b[(i - 1) * HC + c];
            pb += bc * w;
            pg += gc * w;
        }
        Pb[i * HB + tid] = pb;
        Pg[i * HB + tid] = pg;
    }
}

// 512-thread block = TWO samples (s = tid>>8), sharing one wlds staging.
// Rationale: occupancy is empirically pinned at ~2 workgroups/CU regardless
// of LDS (10.75-43.5KB) and VGPR (68-128) -> bigger WGs put more waves/CU.
// LDS: wlds 16384 + haloU 2*6336 + sLast 2*4096 + red 2*64 = 37376 B
//   -> 2 blocks/CU = 74.8KB (87KB proven co-resident in r12).
// VGPR pinned to 128 via amdgpu_num_vgpr (r14/r16: body fits 128 spill-free);
// 16 waves/CU * 128 = exactly the 512-VGPR/SIMD file.
// Rule #20: all register-array loops fully unrolled.
__global__ __attribute__((amdgpu_flat_work_group_size(512, 512), amdgpu_num_vgpr(128)))
void tcn_main(const float* __restrict__ x, const float* __restrict__ in_w,
              const float* __restrict__ in_b, const float* __restrict__ dw_w,
              const float* __restrict__ pw_out, const float* __restrict__ skip_w,
              const float* __restrict__ ln_g, const float* __restrict__ ln_b,
              const float* __restrict__ h1_w, const float* __restrict__ h1_b,
              const float* __restrict__ h2_w, const float* __restrict__ h2_b,
              const float* __restrict__ ws, float* __restrict__ out) {
    __shared__ unsigned wlds[4096];        // current phase's packed weights (16KB, shared)
    __shared__ unsigned haloU[2][48 * 33]; // per-sample packed (u[k],u[32+k]) halo rows
    __shared__ float sLast[2][NL * HC];
    __shared__ float red[2][16];

    const float* Pb = ws + WS_PB;
    const float* Pg = ws + WS_PG;
    const float* Gp = ws + WS_GP;
    const float* Bp = ws + WS_BP;
    const unsigned* WP = (const unsigned*)ws;

    const int tid = threadIdx.x;   // 0..511
    const int s = tid >> 8;        // sample slot within block
    const int t = tid & 255;       // time index within sample
    const int bn = blockIdx.x * 2 + s;
    const int b = bn >> 7, n = bn & 127;
    const int lane = tid & 63;     // == t & 63 (waves never straddle samples)
    const int wv = t >> 6;         // wave index within sample, 0..3

    unsigned* haloS = haloU[s];
    float* sLastS = sLast[s];
    float* redS = red[s];
    // head/last-layer buffers union haloS (halo dead by the time they're used)
    unsigned* wb2u = haloS;                   // 32 uints: last-layer packed w2
    float* hbuf = (float*)(haloS + 64);       // 128 floats
    float* qbuf = hbuf + 128;                 // 128 floats

    // residual state fully register-resident: z2[p] = (ch 2p, ch 2p+1), fp16
    unsigned z2[64];

    // ---------- phase 0: input projection  z[c] = x[b,t,n,:] @ in_w + in_b
    {
        const float* xp = x + (((size_t)b * TT + t) * 128 + n) * 16;
        float xr[16];
#pragma unroll
        for (int d = 0; d < 16; d++) xr[d] = xp[d];
#pragma unroll
        for (int c = 0; c < HC; c += 2) {
            float a0 = in_b[c], a1 = in_b[c + 1];
#pragma unroll
            for (int d = 0; d < 16; d++) {
                a0 = fmaf(xr[d], in_w[d * HC + c], a0);
                a1 = fmaf(xr[d], in_w[d * HC + c + 1], a1);
            }
            z2[c >> 1] = packh2(a0, a1);
        }
    }

    float m_s = 0.f, r_s = 1.f;   // deferred groupnorm scalars

#pragma unroll 1
    for (int L = 0; L < NL; L++) {
        const int dil = 1 << (L & 3);
        const bool lastL = (L == NL - 1);
        const bool active = (!lastL) || (wv == 3);

        // ---------- stage u-phase weights (16KB) into wlds (both samples' threads)
        {
            const uint4* src = (const uint4*)(WP + (size_t)L * 8192);
            uint4* dst = (uint4*)wlds;
#pragma unroll
            for (int i = 0; i < 2; i++) dst[tid + 512 * i] = src[tid + 512 * i];
        }
        __syncthreads();   // B0: Wu staged (also: prev layer's red reads done)

        // ---------- u-phase: packed fp16 accumulation (v_pk_fma_f16)
        unsigned puw[32];
        if (active) {
            __half2 acc2[32];
            const __half2 zero2 = __floats2half2_rn(0.f, 0.f);
#pragma unroll
            for (int j = 0; j < 32; j++) acc2[j] = zero2;
#pragma unroll
            for (int p = 0; p < 64; p++) {     // FULL unroll: z2[p] must stay static
                __half2 zh = __builtin_bit_cast(__half2, z2[p]);
                __half2 zlo = __half2half2(__low2half(zh));
                __half2 zhi = __half2half2(__high2half(zh));
                const uint4* r0 = (const uint4*)(wlds + (2 * p) * 32);
                const uint4* r1 = (const uint4*)(wlds + (2 * p + 1) * 32);
#pragma unroll
                for (int o8 = 0; o8 < 8; o8++) {
                    uint4 q0 = r0[o8];
                    acc2[4 * o8 + 0] = __hfma2(zlo, __builtin_bit_cast(__half2, q0.x), acc2[4 * o8 + 0]);
                    acc2[4 * o8 + 1] = __hfma2(zlo, __builtin_bit_cast(__half2, q0.y), acc2[4 * o8 + 1]);
                    acc2[4 * o8 + 2] = __hfma2(zlo, __builtin_bit_cast(__half2, q0.z), acc2[4 * o8 + 2]);
                    acc2[4 * o8 + 3] = __hfma2(zlo, __builtin_bit_cast(__half2, q0.w), acc2[4 * o8 + 3]);
                }
#pragma unroll
                for (int o8 = 0; o8 < 8; o8++) {
                    uint4 q1 = r1[o8];
                    acc2[4 * o8 + 0] = __hfma2(zhi, __builtin_bit_cast(__half2, q1.x), acc2[4 * o8 + 0]);
                    acc2[4 * o8 + 1] = __hfma2(zhi, __builtin_bit_cast(__half2, q1.y), acc2[4 * o8 + 1]);
                    acc2[4 * o8 + 2] = __hfma2(zhi, __builtin_bit_cast(__half2, q1.z), acc2[4 * o8 + 2]);
                    acc2[4 * o8 + 3] = __hfma2(zhi, __builtin_bit_cast(__half2, q1.w), acc2[4 * o8 + 3]);
                }
            }
            float mr = m_s * r_s;
#pragma unroll
            for (int k = 0; k < 32; k++) {
                const int j = k >> 1;
                float va = (k & 1) ? __high2float(acc2[j])      : __low2float(acc2[j]);
                float vb = (k & 1) ? __high2float(acc2[16 + j]) : __low2float(acc2[16 + j]);
                float ua = fmaf(r_s, va, Pb[L * HB + k]      - mr * Pg[L * HB + k]);
                float ub = fmaf(r_s, vb, Pb[L * HB + 32 + k] - mr * Pg[L * HB + 32 + k]);
                puw[k] = packh2(ua, ub);
            }
            // halo publish: waves 0..2 only (wave 3 rows are never read)
            if (wv < 3 && lane >= 48) {
                int hr = wv * 16 + (lane - 48);
#pragma unroll
                for (int k = 0; k < 32; k++) haloS[hr * 33 + k] = puw[k];
            }
        }
        __syncthreads();   // B1: halo ready AND all u-phase wlds reads done

        // ---------- stage s-phase weights (overwrites wlds) — overlaps conv
        {
            const uint4* src = (const uint4*)(WP + (size_t)L * 8192 + 4096);
            uint4* dst = (uint4*)wlds;
#pragma unroll
            for (int i = 0; i < 2; i++) dst[tid + 512 * i] = src[tid + 512 * i];
        }

        // ---------- conv + gating, IN PLACE: puw[k] (u[k],u[32+k]) -> (w[2k],w[2k+1])
        if (active) {
            const float* dwl = dw_w + (size_t)L * 128 * 3;
            const int d1 = dil, d2 = 2 * dil;
#pragma unroll
            for (int k = 0; k < 32; k++) {
                unsigned pk = puw[k];
                unsigned p1 = __shfl_up(pk, d1);
                unsigned p2 = __shfl_up(pk, d2);
                if (lane < d1) {
                    int tau = t - d1;
                    p1 = (tau < 0) ? 0u : haloS[((tau >> 6) * 16 + (tau & 63) - 48) * 33 + k];
                }
                if (lane < d2) {
                    int tau = t - d2;
                    p2 = (tau < 0) ? 0u : haloS[((tau >> 6) * 16 + (tau & 63) - 48) * 33 + k];
                }
                float uf = loh(pk), ug = hih(pk);
                float m1f = loh(p1), m1g = hih(p1);
                float m2f = loh(p2), m2g = hih(p2);
                float f0 = m2f * dwl[(2 * k) * 3 + 0] + m1f * dwl[(2 * k) * 3 + 1] + uf * dwl[(2 * k) * 3 + 2];
                float f1 = m2f * dwl[(2 * k + 1) * 3 + 0] + m1f * dwl[(2 * k + 1) * 3 + 1] + uf * dwl[(2 * k + 1) * 3 + 2];
                float g0 = m2g * dwl[(64 + 2 * k) * 3 + 0] + m1g * dwl[(64 + 2 * k) * 3 + 1] + ug * dwl[(64 + 2 * k) * 3 + 2];
                float g1 = m2g * dwl[(64 + 2 * k + 1) * 3 + 0] + m1g * dwl[(64 + 2 * k + 1) * 3 + 1] + ug * dwl[(64 + 2 * k + 1) * 3 + 2];
                puw[k] = packh2(fast_tanh(f0) * fast_sig(g0), fast_tanh(f1) * fast_sig(g1));
            }
        }
        __syncthreads();   // B1.5: Po staged AND conv halo-reads done

        if (!lastL) {
            // ---------- s-phase: s_feat via dot2, residual update (deferred GN), stats
            float s1 = 0.f, s2 = 0.f;
            const float mr = m_s * r_s;
            const float* gp = Gp + L * HC;
            const float* bp = Bp + L * HC;
#pragma unroll
            for (int cp = 0; cp < 64; cp++) {  // FULL unroll: z2[cp] must stay static
                const int c = 2 * cp;
                float a0 = 0.f, a1 = 0.f;
                const uint4* r0 = (const uint4*)(wlds + c * 32);
                const uint4* r1 = (const uint4*)(wlds + (c + 1) * 32);
#pragma unroll
                for (int k4 = 0; k4 < 8; k4++) {
                    uint4 q0 = r0[k4], q1 = r1[k4];
                    a0 = fdot2(puw[4 * k4 + 0], q0.x, a0);
                    a0 = fdot2(puw[4 * k4 + 1], q0.y, a0);
                    a0 = fdot2(puw[4 * k4 + 2], q0.z, a0);
                    a0 = fdot2(puw[4 * k4 + 3], q0.w, a0);
                    a1 = fdot2(puw[4 * k4 + 0], q1.x, a1);
                    a1 = fdot2(puw[4 * k4 + 1], q1.y, a1);
                    a1 = fdot2(puw[4 * k4 + 2], q1.z, a1);
                    a1 = fdot2(puw[4 * k4 + 3], q1.w, a1);
                }
                if (t == TT - 1) {
                    sLastS[L * HC + c] = a0;
                    sLastS[L * HC + c + 1] = a1;
                }
                unsigned pz = z2[cp];
                float zo0 = loh(pz), zo1 = hih(pz);
                float g0 = gp[c], g1 = gp[c + 1];
                float zn0 = fmaf(zo0, r_s * g0, (bp[c]     - mr * g0) + a0);
                float zn1 = fmaf(zo1, r_s * g1, (bp[c + 1] - mr * g1) + a1);
                z2[cp] = packh2(zn0, zn1);
                s1 += zn0 + zn1;
                s2 += zn0 * zn0 + zn1 * zn1;
            }
#pragma unroll
            for (int off = 32; off; off >>= 1) {
                s1 += __shfl_xor(s1, off);
                s2 += __shfl_xor(s2, off);
            }
            if (lane == 0) { redS[wv * 2] = s1; redS[wv * 2 + 1] = s2; }
            __syncthreads();   // B2: stats ready AND s-phase wlds reads done
            float S1 = redS[0] + redS[2] + redS[4] + redS[6];
            float S2 = redS[1] + redS[3] + redS[5] + redS[7];
            float mu = S1 * (1.f / 32768.f);
            float var = S2 * (1.f / 32768.f) - mu * mu;
            m_s = mu;
            r_s = rsqrtf(var + 1e-5f);
        } else {
            // last layer: only t==255's gated output matters; parallelize its s-row
            if (t == TT - 1) {
#pragma unroll
                for (int k = 0; k < 32; k++) wb2u[k] = puw[k];
            }
            __syncthreads();   // B2: wb2u ready
            if (t < HC) {
                float a = 0.f;
#pragma unroll
                for (int k = 0; k < 32; k++)
                    a = fdot2(wb2u[k], wlds[t * 32 + k], a);
                sLastS[(NL - 1) * HC + t] = a;
            }
            __syncthreads();   // B3: sLast complete
        }
    }

    // ---------- head: h_last = sum_i skip_w[i] @ sLast[i]; LN; MLP (per sample)
    float hl = 0.f;
    if (t < HC) {
        for (int i = 0; i < NL; i++) {
            const float4* swr = (const float4*)(skip_w + (((size_t)i * HC) + t) * HC);
            const float* sl = sLastS + i * HC;
#pragma unroll 4
            for (int c4 = 0; c4 < 32; c4++) {
                float4 sw = swr[c4];
                hl += sw.x * sl[4 * c4] + sw.y * sl[4 * c4 + 1] + sw.z * sl[4 * c4 + 2] + sw.w * sl[4 * c4 + 3];
            }
        }
        hbuf[t] = hl;
    }
    __syncthreads();
    if (t < 64) {
        float v0 = hbuf[t], v1 = hbuf[t + 64];
        float a = v0 + v1, q = v0 * v0 + v1 * v1;
#pragma unroll
        for (int off = 32; off; off >>= 1) {
            a += __shfl_xor(a, off);
            q += __shfl_xor(q, off);
        }
        if (t == 0) {
            float mu = a * (1.f / 128.f);
            redS[0] = mu;
            redS[1] = rsqrtf(q * (1.f / 128.f) - mu * mu + 1e-5f);
        }
    }
    __syncthreads();
    {
        float mu = redS[0], rs = redS[1];
        if (t < HC) hbuf[t] = (hl - mu) * rs * ln_g[t] + ln_b[t];
    }
    __syncthreads();
    if (t < HC) {
        float q = h1_b[t];
        for (int c = 0; c < HC; c++) q = fmaf(hbuf[c], h1_w[c * HC + t], q);
        q = 0.5f * q * (1.f + erff(q * 0.70710678118654752f));
        qbuf[t] = q;
    }
    __syncthreads();
    if (t < 24) {
        float o = h2_b[t];
        for (int c = 0; c < HC; c++) o = fmaf(qbuf[c], h2_w[c * 24 + t], o);
        out[((size_t)b * 24 + t) * 128 + n] = o;
    }
}

extern "C" void kernel_launch(void* const* d_in, const int* in_sizes, int n_in,
                              void* d_out, int out_size, void* d_ws, size_t ws_size,
                              hipStream_t stream) {
    const float* x      = (const float*)d_in[0];
    const float* in_w   = (const float*)d_in[1];
    const float* in_b   = (const float*)d_in[2];
    const float* pw_in  = (const float*)d_in[3];
    const float* dw_w   = (const float*)d_in[4];
    const float* pw_out = (const float*)d_in[5];
    const float* gn_g   = (const float*)d_in[6];
    const float* gn_b   = (const float*)d_in[7];
    const float* skip_w = (const float*)d_in[8];
    const float* ln_g   = (const float*)d_in[9];
    const float* ln_b   = (const float*)d_in[10];
    const float* h1_w   = (const float*)d_in[11];
    const float* h1_b   = (const float*)d_in[12];
    const float* h2_w   = (const float*)d_in[13];
    const float* h2_b   = (const float*)d_in[14];
    float* out = (float*)d_out;
    float* ws  = (float*)d_ws;

    tcn_setup<<<NL, 256, 0, stream>>>(pw_in, pw_out, gn_g, gn_b, ws);

    tcn_main<<<512, 512, 0, stream>>>(x, in_w, in_b, dw_w, pw_out, skip_w,
                                      ln_g, ln_b, h1_w, h1_b, h2_w, h2_b, ws, out);
}

// Round 18
// 540.664 us; speedup vs baseline: 2.1387x; 2.1387x over previous
//
#include <hip/hip_runtime.h>
#include <hip/hip_fp16.h>
#include <math.h>

#define TT 256
#define HC 128
#define HB 64
#define NL 8

// ---- ws layout (uints) ----
// AU [0, 32768):  u-GEMM A-fragments. Tile (L, mt<4, kt<4): uint4 at
//   WPA[(L*16 + mt*4 + kt)*64 + lane]; elem j of lane = W[16mt+(lane&15)][32kt+8*(lane>>4)+j]
//   where W[o][ch] = pw_in[L][o][ch] * g_prev[ch]  (fp16, j-pairs packed low/high)
// AS [32768, 65536): s-GEMM A-fragments. Tile (L, ms<8, ks<2): uint4 at
//   WPA[8192 + (L*16 + ms*2 + ks)*64 + lane]; elem j = pw_out[L][16ms+(lane&15)][32ks+8*(lane>>4)+j]
// float view: Pb @65536, Pg @66048, Gp @66560, Bp @67584  (same as prior rounds)
#define WS_PB  65536
#define WS_PG  66048
#define WS_GP  66560
#define WS_BP  67584

typedef _Float16 f16x8 __attribute__((ext_vector_type(8)));
typedef float f32x4 __attribute__((ext_vector_type(4)));

__device__ __forceinline__ f16x8 asf16x8(uint4 v) {
    union { uint4 u; f16x8 h; } cv; cv.u = v; return cv.h;
}
__device__ __forceinline__ f32x4 mfma16(uint4 a, uint4 b, f32x4 c) {
    return __builtin_amdgcn_mfma_f32_16x16x32_f16(asf16x8(a), asf16x8(b), c, 0, 0, 0);
}
__device__ __forceinline__ float fast_tanh(float x) {
    float e = __expf(2.f * fabsf(x));
    float r = 1.f - 2.f / (1.f + e);
    return copysignf(r, x);
}
__device__ __forceinline__ float fast_sig(float x) {
    return 1.f / (1.f + __expf(-x));
}
__device__ __forceinline__ unsigned packh2(float a, float b) {
    __half2 h = __floats2half2_rn(a, b);
    return __builtin_bit_cast(unsigned, h);
}
__device__ __forceinline__ float loh(unsigned u) {
    return __low2float(__builtin_bit_cast(__half2, u));
}
__device__ __forceinline__ float hih(unsigned u) {
    return __high2float(__builtin_bit_cast(__half2, u));
}
__device__ __forceinline__ unsigned u4get(uint4 v, int q) {
    return q == 0 ? v.x : q == 1 ? v.y : q == 2 ? v.z : v.w;  // q is compile-time
}

__global__ __launch_bounds__(256)
void tcn_setup(const float* __restrict__ pw_in, const float* __restrict__ pw_out,
               const float* __restrict__ gn_g, const float* __restrict__ gn_b,
               float* __restrict__ ws) {
    const int i = blockIdx.x;      // layer
    const int tid = threadIdx.x;   // 256 threads
    uint4* WPA = (uint4*)ws;
    float* Pb = ws + WS_PB;
    float* Pg = ws + WS_PG;
    float* Gp = ws + WS_GP;
    float* Bp = ws + WS_BP;

    if (tid < HC) {
        float g  = (i == 0) ? 1.f : gn_g[(i - 1) * HC + tid];
        float bb = (i == 0) ? 0.f : gn_b[(i - 1) * HC + tid];
        Gp[i * HC + tid] = g;
        Bp[i * HC + tid] = bb;
    }
    // AU fragments
    for (int e = tid; e < 16 * 64; e += 256) {
        int tile = e >> 6, lane = e & 63;
        int mt = tile >> 2, kt = tile & 3;
        int o = 16 * mt + (lane & 15);
        int chb = 32 * kt + 8 * (lane >> 4);
        uint4 v;
        unsigned vq[4];
        for (int q = 0; q < 4; q++) {
            int ch = chb + 2 * q;
            float g0 = (i == 0) ? 1.f : gn_g[(i - 1) * HC + ch];
            float g1 = (i == 0) ? 1.f : gn_g[(i - 1) * HC + ch + 1];
            float w0 = pw_in[((size_t)i * HB + o) * HC + ch] * g0;
            float w1 = pw_in[((size_t)i * HB + o) * HC + ch + 1] * g1;
            vq[q] = packh2(w0, w1);
        }
        v.x = vq[0]; v.y = vq[1]; v.z = vq[2]; v.w = vq[3];
        WPA[((size_t)i * 16 + tile) * 64 + lane] = v;
    }
    // AS fragments
    for (int e = tid; e < 16 * 64; e += 256) {
        int tile = e >> 6, lane = e & 63;
        int ms = tile >> 1, ks = tile & 1;
        int o = 16 * ms + (lane & 15);
        int chb = 32 * ks + 8 * (lane >> 4);
        uint4 v;
        unsigned vq[4];
        for (int q = 0; q < 4; q++) {
            int ch = chb + 2 * q;
            float w0 = pw_out[((size_t)i * HC + o) * HB + ch];
            float w1 = pw_out[((size_t)i * HC + o) * HB + ch + 1];
            vq[q] = packh2(w0, w1);
        }
        v.x = vq[0]; v.y = vq[1]; v.z = vq[2]; v.w = vq[3];
        WPA[8192 + ((size_t)i * 16 + tile) * 64 + lane] = v;
    }
    if (tid < HB) {
        float pb = 0.f, pg = 0.f;
        for (int c = 0; c < HC; c++) {
            float w = pw_in[((size_t)i * HB + tid) * HC + c];
            float gc = (i == 0) ? 1.f : gn_g[(i - 1) * HC + c];
            float bc = (i == 0) ? 0.f : gn_b[(i - 1) * HC + c];
            pb += bc * w;
            pg += gc * w;
        }
        Pb[i * HB + tid] = pb;
        Pg[i * HB + tid] = pg;
    }
}

// MFMA formulation. Per wave (64 t): u = W@Z and s = Po@w~ as 16x16x32 f16 MFMAs.
// z persistently in B-fragment registers; conv output lands natively in s-GEMM
// B-layout; weights read as prepacked A-fragments from global (L2).
// LDS: scratch 16448B (z-bounce / head bufs) + haloB 6528 + sLast 4096 + red 64 = ~27KB.
__global__ __launch_bounds__(256)
void tcn_main(const float* __restrict__ x, const float* __restrict__ in_w,
              const float* __restrict__ in_b, const float* __restrict__ dw_w,
              const float* __restrict__ pw_out, const float* __restrict__ skip_w,
              const float* __restrict__ ln_g, const float* __restrict__ ln_b,
              const float* __restrict__ h1_w, const float* __restrict__ h1_b,
              const float* __restrict__ h2_w, const float* __restrict__ h2_b,
              const float* __restrict__ ws, float* __restrict__ out) {
    __shared__ unsigned scratch[16 * 257];    // z-bounce slices (padded); head bufs later
    __shared__ unsigned haloB[3 * 32 * 17];   // fp16-pair u halo: [wv][o_pair<32][col<16] pad17
    __shared__ float sLast[NL * HC];
    __shared__ float red[16];
    float* hbuf = (float*)scratch;            // head reuse
    float* qbuf = hbuf + 128;

    const float* Pb = ws + WS_PB;
    const float* Pg = ws + WS_PG;
    const float* Gp = ws + WS_GP;
    const float* Bp = ws + WS_BP;
    const uint4* WPA = (const uint4*)ws;

    const int t = threadIdx.x;     // 0..255
    const int bn = blockIdx.x;
    const int b = bn >> 7, n = bn & 127;
    const int lane = t & 63;
    const int wv = t >> 6;
    const int cc = lane & 15;      // col within 16-wide tile
    const int l4 = lane >> 4;

    // ---------- input projection (per-thread, as before) ----------
    unsigned z2[64];
    {
        const float* xp = x + (((size_t)b * TT + t) * 128 + n) * 16;
        float xr[16];
#pragma unroll
        for (int d = 0; d < 16; d++) xr[d] = xp[d];
#pragma unroll
        for (int c = 0; c < HC; c += 2) {
            float a0 = in_b[c], a1 = in_b[c + 1];
#pragma unroll
            for (int d = 0; d < 16; d++) {
                a0 = fmaf(xr[d], in_w[d * HC + c], a0);
                a1 = fmaf(xr[d], in_w[d * HC + c + 1], a1);
            }
            z2[c >> 1] = packh2(a0, a1);
        }
    }

    // ---------- bounce z to B-fragment layout ----------
    // zB[kt][nt]: elem j = z[ch=32kt+8*l4+j][t = 64wv + 16nt + cc]
    uint4 zB[4][4];
#pragma unroll
    for (int kt = 0; kt < 4; kt++) {
#pragma unroll
        for (int q = 0; q < 16; q++) scratch[q * 257 + t] = z2[16 * kt + q];
        __syncthreads();
#pragma unroll
        for (int nt = 0; nt < 4; nt++) {
            int col = 64 * wv + nt * 16 + cc;
            uint4 v;
            v.x = scratch[(4 * l4 + 0) * 257 + col];
            v.y = scratch[(4 * l4 + 1) * 257 + col];
            v.z = scratch[(4 * l4 + 2) * 257 + col];
            v.w = scratch[(4 * l4 + 3) * 257 + col];
            zB[kt][nt] = v;
        }
        __syncthreads();
    }

    float m_s = 0.f, r_s = 1.f;

#pragma unroll 1
    for (int L = 0; L < NL; L++) {
        const int dil = 1 << (L & 3), d1 = dil, d2 = 2 * dil;
        const bool lastL = (L == NL - 1);
        const bool act = (!lastL) || (wv == 3);
        const float mr = m_s * r_s;

        // ---------- u-GEMM: cu[mt][nt] = r_s*(W@Z) + Pb - mr*Pg ----------
        f32x4 cu[4][4];
        if (act) {
            const uint4* AU = WPA + (size_t)L * 16 * 64;
#pragma unroll
            for (int mt = 0; mt < 4; mt++) {
                uint4 a0 = AU[(mt * 4 + 0) * 64 + lane];
                uint4 a1 = AU[(mt * 4 + 1) * 64 + lane];
                uint4 a2 = AU[(mt * 4 + 2) * 64 + lane];
                uint4 a3 = AU[(mt * 4 + 3) * 64 + lane];
                float4 pbv = *(const float4*)(Pb + L * HB + 16 * mt + 4 * l4);
                float4 pgv = *(const float4*)(Pg + L * HB + 16 * mt + 4 * l4);
#pragma unroll
                for (int nt = 0; nt < 4; nt++) {
                    f32x4 acc = {0.f, 0.f, 0.f, 0.f};
                    acc = mfma16(a0, zB[0][nt], acc);
                    acc = mfma16(a1, zB[1][nt], acc);
                    acc = mfma16(a2, zB[2][nt], acc);
                    acc = mfma16(a3, zB[3][nt], acc);
                    acc[0] = fmaf(r_s, acc[0], pbv.x - mr * pgv.x);
                    acc[1] = fmaf(r_s, acc[1], pbv.y - mr * pgv.y);
                    acc[2] = fmaf(r_s, acc[2], pbv.z - mr * pgv.z);
                    acc[3] = fmaf(r_s, acc[3], pbv.w - mr * pgv.w);
                    cu[mt][nt] = acc;
                }
            }
            // halo publish (u at nt=3 -> cols 48..63 of this wave)
            if (wv < 3) {
#pragma unroll
                for (int mt = 0; mt < 4; mt++)
#pragma unroll
                    for (int rp = 0; rp < 2; rp++)
                        haloB[wv * (32 * 17) + (8 * mt + 2 * l4 + rp) * 17 + cc] =
                            packh2(cu[mt][3][2 * rp], cu[mt][3][2 * rp + 1]);
            }
        }
        __syncthreads();   // B1: halo ready

        // ---------- conv + gating -> Bw (s-GEMM B-fragments, zero shuffles) ----------
        unsigned bwv[2][4][4];
        if (act) {
            const float* dwl = dw_w + (size_t)L * 384;
#pragma unroll
            for (int mtf = 0; mtf < 2; mtf++) {
#pragma unroll
                for (int r = 0; r < 4; r++) {
                    const int o = 16 * mtf + 4 * l4 + r;
                    const float* df0 = dwl + (2 * o) * 3;
                    const float* df1 = dwl + (2 * o + 1) * 3;
                    const float* dg0 = dwl + (64 + 2 * o) * 3;
                    const float* dg1 = dwl + (64 + 2 * o + 1) * 3;
                    const int hrowf = (8 * mtf + 2 * l4 + (r >> 1)) * 17;
                    const int hrowg = (8 * (mtf + 2) + 2 * l4 + (r >> 1)) * 17;
                    const int hbase = (wv > 0 ? wv - 1 : 0) * (32 * 17);
#pragma unroll
                    for (int nt = 0; nt < 4; nt++) {
                        float uf = cu[mtf][nt][r];
                        float ug = cu[mtf + 2][nt][r];
                        float m1f, m1g, m2f, m2g;
                        {   // tap at d1
                            const int cd = (cc - d1) & 15;
                            const int src = (lane & 48) | cd;
                            float sf = __shfl(uf, src), sg = __shfl(ug, src);
                            float pf, pg_;
                            if (nt > 0) {
                                pf  = __shfl(cu[mtf][nt - 1][r], src);
                                pg_ = __shfl(cu[mtf + 2][nt - 1][r], src);
                            } else {
                                unsigned hf = haloB[hbase + hrowf + cd];
                                unsigned hg = haloB[hbase + hrowg + cd];
                                pf  = (r & 1) ? hih(hf) : loh(hf);
                                pg_ = (r & 1) ? hih(hg) : loh(hg);
                                if (wv == 0) { pf = 0.f; pg_ = 0.f; }
                            }
                            bool in = (cc >= d1);
                            m1f = in ? sf : pf;  m1g = in ? sg : pg_;
                        }
                        {   // tap at d2
                            const int cd = (cc - d2) & 15;
                            const int src = (lane & 48) | cd;
                            float sf = __shfl(uf, src), sg = __shfl(ug, src);
                            float pf, pg_;
                            if (nt > 0) {
                                pf  = __shfl(cu[mtf][nt - 1][r], src);
                                pg_ = __shfl(cu[mtf + 2][nt - 1][r], src);
                            } else {
                                unsigned hf = haloB[hbase + hrowf + cd];
                                unsigned hg = haloB[hbase + hrowg + cd];
                                pf  = (r & 1) ? hih(hf) : loh(hf);
                                pg_ = (r & 1) ? hih(hg) : loh(hg);
                                if (wv == 0) { pf = 0.f; pg_ = 0.f; }
                            }
                            bool in = (cc >= d2);
                            m2f = in ? sf : pf;  m2g = in ? sg : pg_;
                        }
                        float f0 = m2f * df0[0] + m1f * df0[1] + uf * df0[2];
                        float f1 = m2f * df1[0] + m1f * df1[1] + uf * df1[2];
                        float g0 = m2g * dg0[0] + m1g * dg0[1] + ug * dg0[2];
                        float g1 = m2g * dg1[0] + m1g * dg1[1] + ug * dg1[2];
                        bwv[mtf][nt][r] =
                            packh2(fast_tanh(f0) * fast_sig(g0), fast_tanh(f1) * fast_sig(g1));
                    }
                }
            }
        }

        // ---------- s-GEMM + sLast + z-update + stats ----------
        float s1 = 0.f, s2 = 0.f;
        if (act) {
            uint4 Bw[2][4];
#pragma unroll
            for (int ks = 0; ks < 2; ks++)
#pragma unroll
                for (int nt = 0; nt < 4; nt++) {
                    uint4 v;
                    v.x = bwv[ks][nt][0]; v.y = bwv[ks][nt][1];
                    v.z = bwv[ks][nt][2]; v.w = bwv[ks][nt][3];
                    Bw[ks][nt] = v;
                }
            const uint4* AS = WPA + 8192 + (size_t)L * 16 * 64;
#pragma unroll
            for (int kt = 0; kt < 4; kt++) {
                f32x4 cs[2][4];
#pragma unroll
                for (int lo = 0; lo < 2; lo++) {
                    const int ms = 2 * kt + lo;
                    uint4 a0 = AS[(ms * 2 + 0) * 64 + lane];
                    uint4 a1 = AS[(ms * 2 + 1) * 64 + lane];
#pragma unroll
                    for (int nt = 0; nt < 4; nt++) {
                        f32x4 acc = {0.f, 0.f, 0.f, 0.f};
                        acc = mfma16(a0, Bw[0][nt], acc);
                        acc = mfma16(a1, Bw[1][nt], acc);
                        cs[lo][nt] = acc;
                    }
                }
                if (wv == 3 && cc == 15) {
#pragma unroll
                    for (int lo = 0; lo < 2; lo++)
#pragma unroll
                        for (int r = 0; r < 4; r++)
                            sLast[L * HC + 16 * (2 * kt + lo) + 4 * l4 + r] = cs[lo][3][r];
                }
                if (!lastL) {
                    const int losel = l4 >> 1;
#pragma unroll
                    for (int nt = 0; nt < 4; nt++) {
                        unsigned zp[4];
#pragma unroll
                        for (int q = 0; q < 4; q++) {
                            // s_feat for ch = 32kt+8*l4+2q (+1): source lane/regs
                            const int src = (((2 * l4 + (q >> 1)) & 3) << 4) | cc;
                            float v00 = __shfl(cs[0][nt][(2 * q) & 3], src);
                            float v01 = __shfl(cs[1][nt][(2 * q) & 3], src);
                            float sf0 = losel ? v01 : v00;
                            float v10 = __shfl(cs[0][nt][(2 * q + 1) & 3], src);
                            float v11 = __shfl(cs[1][nt][(2 * q + 1) & 3], src);
                            float sf1 = losel ? v11 : v10;
                            unsigned zold = u4get(zB[kt][nt], q);
                            float zo0 = loh(zold), zo1 = hih(zold);
                            float2 gv = *(const float2*)(Gp + L * HC + 32 * kt + 8 * l4 + 2 * q);
                            float2 bv = *(const float2*)(Bp + L * HC + 32 * kt + 8 * l4 + 2 * q);
                            float zn0 = fmaf(zo0, r_s * gv.x, (bv.x - mr * gv.x) + sf0);
                            float zn1 = fmaf(zo1, r_s * gv.y, (bv.y - mr * gv.y) + sf1);
                            zp[q] = packh2(zn0, zn1);
                            s1 += zn0 + zn1;
                            s2 += zn0 * zn0 + zn1 * zn1;
                        }
                        uint4 v;
                        v.x = zp[0]; v.y = zp[1]; v.z = zp[2]; v.w = zp[3];
                        zB[kt][nt] = v;
                    }
                }
            }
        }
        if (!lastL) {
#pragma unroll
            for (int off = 32; off; off >>= 1) {
                s1 += __shfl_xor(s1, off);
                s2 += __shfl_xor(s2, off);
            }
            if (lane == 0) { red[wv * 2] = s1; red[wv * 2 + 1] = s2; }
            __syncthreads();   // B2
            float S1 = red[0] + red[2] + red[4] + red[6];
            float S2 = red[1] + red[3] + red[5] + red[7];
            float mu = S1 * (1.f / 32768.f);
            float var = S2 * (1.f / 32768.f) - mu * mu;
            m_s = mu;
            r_s = rsqrtf(var + 1e-5f);
        }
    }
    __syncthreads();   // sLast complete; scratch free for head bufs

    // ---------- head: h_last = sum_i skip_w[i] @ sLast[i]; LN; MLP ----------
    float hl = 0.f;
    if (t < HC) {
        for (int i = 0; i < NL; i++) {
            const float4* swr = (const float4*)(skip_w + (((size_t)i * HC) + t) * HC);
            const float* sl = sLast + i * HC;
#pragma unroll 4
            for (int c4 = 0; c4 < 32; c4++) {
                float4 sw = swr[c4];
                hl += sw.x * sl[4 * c4] + sw.y * sl[4 * c4 + 1] + sw.z * sl[4 * c4 + 2] + sw.w * sl[4 * c4 + 3];
            }
        }
        hbuf[t] = hl;
    }
    __syncthreads();
    if (t < 64) {
        float v0 = hbuf[t], v1 = hbuf[t + 64];
        float a = v0 + v1, q = v0 * v0 + v1 * v1;
#pragma unroll
        for (int off = 32; off; off >>= 1) {
            a += __shfl_xor(a, off);
            q += __shfl_xor(q, off);
        }
        if (t == 0) {
            float mu = a * (1.f / 128.f);
            red[0] = mu;
            red[1] = rsqrtf(q * (1.f / 128.f) - mu * mu + 1e-5f);
        }
    }
    __syncthreads();
    {
        float mu = red[0], rs = red[1];
        if (t < HC) hbuf[t] = (hl - mu) * rs * ln_g[t] + ln_b[t];
    }
    __syncthreads();
    if (t < HC) {
        float q = h1_b[t];
        for (int c = 0; c < HC; c++) q = fmaf(hbuf[c], h1_w[c * HC + t], q);
        q = 0.5f * q * (1.f + erff(q * 0.70710678118654752f));
        qbuf[t] = q;
    }
    __syncthreads();
    if (t < 24) {
        float o = h2_b[t];
        for (int c = 0; c < HC; c++) o = fmaf(qbuf[c], h2_w[c * 24 + t], o);
        out[((size_t)b * 24 + t) * 128 + n] = o;
    }
}

extern "C" void kernel_launch(void* const* d_in, const int* in_sizes, int n_in,
                              void* d_out, int out_size, void* d_ws, size_t ws_size,
                              hipStream_t stream) {
    const float* x      = (const float*)d_in[0];
    const float* in_w   = (const float*)d_in[1];
    const float* in_b   = (const float*)d_in[2];
    const float* pw_in  = (const float*)d_in[3];
    const float* dw_w   = (const float*)d_in[4];
    const float* pw_out = (const float*)d_in[5];
    const float* gn_g   = (const float*)d_in[6];
    const float* gn_b   = (const float*)d_in[7];
    const float* skip_w = (const float*)d_in[8];
    const float* ln_g   = (const float*)d_in[9];
    const float* ln_b   = (const float*)d_in[10];
    const float* h1_w   = (const float*)d_in[11];
    const float* h1_b   = (const float*)d_in[12];
    const float* h2_w   = (const float*)d_in[13];
    const float* h2_b   = (const float*)d_in[14];
    float* out = (float*)d_out;
    float* ws  = (float*)d_ws;

    tcn_setup<<<NL, 256, 0, stream>>>(pw_in, pw_out, gn_g, gn_b, ws);

    tcn_main<<<1024, 256, 0, stream>>>(x, in_w, in_b, dw_w, pw_out, skip_w,
                                       ln_g, ln_b, h1_w, h1_b, h2_w, h2_b, ws, out);
}

// Round 19
// 488.938 us; speedup vs baseline: 2.3650x; 1.1058x over previous
//
#include <hip/hip_runtime.h>
#include <hip/hip_fp16.h>
#include <math.h>

#define TT 256
#define HC 128
#define HB 64
#define NL 8

// ---- ws layout (uints) ----
// AU [0, 32768):  u-GEMM A-fragments. Tile (L, mt<4, kt<4): uint4 at
//   WPA[(L*16 + mt*4 + kt)*64 + lane]; elem j = W[16mt+(lane&15)][32kt+8*(lane>>4)+j]
// AS [32768, 65536): s-GEMM A-fragments. Tile (L, ms<8, ks<2): uint4 at
//   WPA[8192 + (L*16 + ms*2 + ks)*64 + lane]
// float view: Pb @65536, Pg @66048, Gp @66560, Bp @67584
#define WS_PB  65536
#define WS_PG  66048
#define WS_GP  66560
#define WS_BP  67584

typedef _Float16 f16x8 __attribute__((ext_vector_type(8)));
typedef float f32x4 __attribute__((ext_vector_type(4)));

__device__ __forceinline__ f16x8 asf16x8(uint4 v) {
    union { uint4 u; f16x8 h; } cv; cv.u = v; return cv.h;
}
__device__ __forceinline__ f32x4 mfma16(uint4 a, uint4 b, f32x4 c) {
    return __builtin_amdgcn_mfma_f32_16x16x32_f16(asf16x8(a), asf16x8(b), c, 0, 0, 0);
}
__device__ __forceinline__ float fast_tanh(float x) {
    float e = __expf(2.f * fabsf(x));
    float r = 1.f - 2.f / (1.f + e);
    return copysignf(r, x);
}
__device__ __forceinline__ float fast_sig(float x) {
    return 1.f / (1.f + __expf(-x));
}
__device__ __forceinline__ unsigned packh2(float a, float b) {
    __half2 h = __floats2half2_rn(a, b);
    return __builtin_bit_cast(unsigned, h);
}
__device__ __forceinline__ float loh(unsigned u) {
    return __low2float(__builtin_bit_cast(__half2, u));
}
__device__ __forceinline__ float hih(unsigned u) {
    return __high2float(__builtin_bit_cast(__half2, u));
}
__device__ __forceinline__ unsigned u4get(uint4 v, int q) {
    return q == 0 ? v.x : q == 1 ? v.y : q == 2 ? v.z : v.w;  // q compile-time
}

__global__ __launch_bounds__(256)
void tcn_setup(const float* __restrict__ pw_in, const float* __restrict__ pw_out,
               const float* __restrict__ gn_g, const float* __restrict__ gn_b,
               float* __restrict__ ws) {
    const int i = blockIdx.x;      // layer
    const int tid = threadIdx.x;   // 256 threads
    uint4* WPA = (uint4*)ws;
    float* Pb = ws + WS_PB;
    float* Pg = ws + WS_PG;
    float* Gp = ws + WS_GP;
    float* Bp = ws + WS_BP;

    if (tid < HC) {
        float g  = (i == 0) ? 1.f : gn_g[(i - 1) * HC + tid];
        float bb = (i == 0) ? 0.f : gn_b[(i - 1) * HC + tid];
        Gp[i * HC + tid] = g;
        Bp[i * HC + tid] = bb;
    }
    // AU fragments
    for (int e = tid; e < 16 * 64; e += 256) {
        int tile = e >> 6, lane = e & 63;
        int mt = tile >> 2, kt = tile & 3;
        int o = 16 * mt + (lane & 15);
        int chb = 32 * kt + 8 * (lane >> 4);
        uint4 v;
        unsigned vq[4];
        for (int q = 0; q < 4; q++) {
            int ch = chb + 2 * q;
            float g0 = (i == 0) ? 1.f : gn_g[(i - 1) * HC + ch];
            float g1 = (i == 0) ? 1.f : gn_g[(i - 1) * HC + ch + 1];
            float w0 = pw_in[((size_t)i * HB + o) * HC + ch] * g0;
            float w1 = pw_in[((size_t)i * HB + o) * HC + ch + 1] * g1;
            vq[q] = packh2(w0, w1);
        }
        v.x = vq[0]; v.y = vq[1]; v.z = vq[2]; v.w = vq[3];
        WPA[((size_t)i * 16 + tile) * 64 + lane] = v;
    }
    // AS fragments
    for (int e = tid; e < 16 * 64; e += 256) {
        int tile = e >> 6, lane = e & 63;
        int ms = tile >> 1, ks = tile & 1;
        int o = 16 * ms + (lane & 15);
        int chb = 32 * ks + 8 * (lane >> 4);
        uint4 v;
        unsigned vq[4];
        for (int q = 0; q < 4; q++) {
            int ch = chb + 2 * q;
            float w0 = pw_out[((size_t)i * HC + o) * HB + ch];
            float w1 = pw_out[((size_t)i * HC + o) * HB + ch + 1];
            vq[q] = packh2(w0, w1);
        }
        v.x = vq[0]; v.y = vq[1]; v.z = vq[2]; v.w = vq[3];
        WPA[8192 + ((size_t)i * 16 + tile) * 64 + lane] = v;
    }
    if (tid < HB) {
        float pb = 0.f, pg = 0.f;
        for (int c = 0; c < HC; c++) {
            float w = pw_in[((size_t)i * HB + tid) * HC + c];
            float gc = (i == 0) ? 1.f : gn_g[(i - 1) * HC + c];
            float bc = (i == 0) ? 0.f : gn_b[(i - 1) * HC + c];
            pb += bc * w;
            pg += gc * w;
        }
        Pb[i * HB + tid] = pb;
        Pg[i * HB + tid] = pg;
    }
}

// MFMA formulation (r18-verified layouts) with LDS-op surgery:
//  - u packed to fp16 pairs: one shuffle carries 2 channels (conv shfl halved x2)
//  - source-side select: 1 shuffle per tap instead of 2 (src lane pre-picks tile)
//  - z-update C->B conversion via per-wave LDS bounce (128 b32 ops) instead of 256 shfl
// LDS: scratch 16896 + haloB 6528 + sLast 4096 + red 64 = 27584 B.
__global__ __launch_bounds__(256)
void tcn_main(const float* __restrict__ x, const float* __restrict__ in_w,
              const float* __restrict__ in_b, const float* __restrict__ dw_w,
              const float* __restrict__ pw_out, const float* __restrict__ skip_w,
              const float* __restrict__ ln_g, const float* __restrict__ ln_b,
              const float* __restrict__ h1_w, const float* __restrict__ h1_b,
              const float* __restrict__ h2_w, const float* __restrict__ h2_b,
              const float* __restrict__ ws, float* __restrict__ out) {
    __shared__ unsigned scratch[4224];        // init z-bounce (16x257) / per-wave s-bounce (4x16x66) / head bufs
    __shared__ unsigned haloB[3 * 32 * 17];   // fp16-pair u halo: [wv][row pair<32][col<16] pad17
    __shared__ float sLast[NL * HC];
    __shared__ float red[16];
    float* hbuf = (float*)scratch;            // head reuse
    float* qbuf = hbuf + 128;

    const float* Pb = ws + WS_PB;
    const float* Pg = ws + WS_PG;
    const float* Gp = ws + WS_GP;
    const float* Bp = ws + WS_BP;
    const uint4* WPA = (const uint4*)ws;

    const int t = threadIdx.x;     // 0..255
    const int bn = blockIdx.x;
    const int b = bn >> 7, n = bn & 127;
    const int lane = t & 63;
    const int wv = t >> 6;
    const int cc = lane & 15;      // col within 16-wide tile
    const int l4 = lane >> 4;

    // ---------- input projection ----------
    unsigned z2[64];
    {
        const float* xp = x + (((size_t)b * TT + t) * 128 + n) * 16;
        float xr[16];
#pragma unroll
        for (int d = 0; d < 16; d++) xr[d] = xp[d];
#pragma unroll
        for (int c = 0; c < HC; c += 2) {
            float a0 = in_b[c], a1 = in_b[c + 1];
#pragma unroll
            for (int d = 0; d < 16; d++) {
                a0 = fmaf(xr[d], in_w[d * HC + c], a0);
                a1 = fmaf(xr[d], in_w[d * HC + c + 1], a1);
            }
            z2[c >> 1] = packh2(a0, a1);
        }
    }

    // ---------- bounce z to B-fragment layout ----------
    uint4 zB[4][4];
#pragma unroll
    for (int kt = 0; kt < 4; kt++) {
#pragma unroll
        for (int q = 0; q < 16; q++) scratch[q * 257 + t] = z2[16 * kt + q];
        __syncthreads();
#pragma unroll
        for (int nt = 0; nt < 4; nt++) {
            int col = 64 * wv + nt * 16 + cc;
            uint4 v;
            v.x = scratch[(4 * l4 + 0) * 257 + col];
            v.y = scratch[(4 * l4 + 1) * 257 + col];
            v.z = scratch[(4 * l4 + 2) * 257 + col];
            v.w = scratch[(4 * l4 + 3) * 257 + col];
            zB[kt][nt] = v;
        }
        __syncthreads();
    }

    float m_s = 0.f, r_s = 1.f;

#pragma unroll 1
    for (int L = 0; L < NL; L++) {
        const int dil = 1 << (L & 3), d1 = dil, d2 = 2 * dil;
        const bool lastL = (L == NL - 1);
        const bool act = (!lastL) || (wv == 3);
        const float mr = m_s * r_s;

        // ---------- u-GEMM, affine, pack to fp16 pairs ----------
        // pu[mt][nt][rp] = (u[16mt+4l4+2rp][col], u[...+2rp+1][col]), col=16nt+cc
        unsigned pu[4][4][2];
        if (act) {
            const uint4* AU = WPA + (size_t)L * 16 * 64;
#pragma unroll
            for (int mt = 0; mt < 4; mt++) {
                uint4 a0 = AU[(mt * 4 + 0) * 64 + lane];
                uint4 a1 = AU[(mt * 4 + 1) * 64 + lane];
                uint4 a2 = AU[(mt * 4 + 2) * 64 + lane];
                uint4 a3 = AU[(mt * 4 + 3) * 64 + lane];
                float4 pbv = *(const float4*)(Pb + L * HB + 16 * mt + 4 * l4);
                float4 pgv = *(const float4*)(Pg + L * HB + 16 * mt + 4 * l4);
#pragma unroll
                for (int nt = 0; nt < 4; nt++) {
                    f32x4 acc = {0.f, 0.f, 0.f, 0.f};
                    acc = mfma16(a0, zB[0][nt], acc);
                    acc = mfma16(a1, zB[1][nt], acc);
                    acc = mfma16(a2, zB[2][nt], acc);
                    acc = mfma16(a3, zB[3][nt], acc);
                    float u0 = fmaf(r_s, acc[0], pbv.x - mr * pgv.x);
                    float u1 = fmaf(r_s, acc[1], pbv.y - mr * pgv.y);
                    float u2 = fmaf(r_s, acc[2], pbv.z - mr * pgv.z);
                    float u3 = fmaf(r_s, acc[3], pbv.w - mr * pgv.w);
                    pu[mt][nt][0] = packh2(u0, u1);
                    pu[mt][nt][1] = packh2(u2, u3);
                }
            }
            // halo publish (tile nt=3 -> cols 48..63 of this wave)
            if (wv < 3) {
#pragma unroll
                for (int mt = 0; mt < 4; mt++)
#pragma unroll
                    for (int rp = 0; rp < 2; rp++)
                        haloB[wv * (32 * 17) + (8 * mt + 2 * l4 + rp) * 17 + cc] = pu[mt][3][rp];
            }
        }
        __syncthreads();   // B1: halo ready

        // ---------- conv + gating -> bwv (s-GEMM B-fragments) ----------
        unsigned bwv[2][4][4];
        if (act) {
            const float* dwl = dw_w + (size_t)L * 384;
            const int hb = (wv > 0 ? wv - 1 : 0) * (32 * 17);
#pragma unroll
            for (int mtf = 0; mtf < 2; mtf++) {
#pragma unroll
                for (int rp = 0; rp < 2; rp++) {
                    unsigned hf = 0u, hg = 0u;
                    if (wv > 0) {
                        hf = haloB[hb + (8 * mtf + 2 * l4 + rp) * 17 + cc];
                        hg = haloB[hb + (8 * (mtf + 2) + 2 * l4 + rp) * 17 + cc];
                    }
                    unsigned m1f[4], m1g[4], m2f[4], m2g[4];
                    {   // tap d1: source-side select, one shuffle per value
                        const int srcl = (lane & 48) | ((cc - d1) & 15);
                        const bool own = (cc <= 15 - d1);
#pragma unroll
                        for (int nt = 0; nt < 4; nt++) {
                            unsigned wf = own ? pu[mtf][nt][rp]
                                              : (nt > 0 ? pu[mtf][nt - 1][rp] : hf);
                            unsigned wg = own ? pu[mtf + 2][nt][rp]
                                              : (nt > 0 ? pu[mtf + 2][nt - 1][rp] : hg);
                            m1f[nt] = __shfl(wf, srcl);
                            m1g[nt] = __shfl(wg, srcl);
                        }
                    }
                    {   // tap d2
                        const int srcl = (lane & 48) | ((cc - d2) & 15);
                        const bool own = (cc <= 15 - d2);
#pragma unroll
                        for (int nt = 0; nt < 4; nt++) {
                            unsigned wf = own ? pu[mtf][nt][rp]
                                              : (nt > 0 ? pu[mtf][nt - 1][rp] : hf);
                            unsigned wg = own ? pu[mtf + 2][nt][rp]
                                              : (nt > 0 ? pu[mtf + 2][nt - 1][rp] : hg);
                            m2f[nt] = __shfl(wf, srcl);
                            m2g[nt] = __shfl(wg, srcl);
                        }
                    }
                    // gating: rows o=16mtf+4l4+2rp (lo) and o+1 (hi)
                    const int o = 16 * mtf + 4 * l4 + 2 * rp;
                    const float* df = dwl + (2 * o) * 3;        // f rows 2o..2o+3
                    const float* dg = dwl + (64 + 2 * o) * 3;   // gate rows
#pragma unroll
                    for (int nt = 0; nt < 4; nt++) {
                        float uf0 = loh(pu[mtf][nt][rp]),     uf1 = hih(pu[mtf][nt][rp]);
                        float ug0 = loh(pu[mtf + 2][nt][rp]), ug1 = hih(pu[mtf + 2][nt][rp]);
                        float a1f0 = loh(m1f[nt]), a1f1 = hih(m1f[nt]);
                        float a2f0 = loh(m2f[nt]), a2f1 = hih(m2f[nt]);
                        float a1g0 = loh(m1g[nt]), a1g1 = hih(m1g[nt]);
                        float a2g0 = loh(m2g[nt]), a2g1 = hih(m2g[nt]);
                        float f0 = a2f0 * df[0] + a1f0 * df[1]  + uf0 * df[2];
                        float f1 = a2f0 * df[3] + a1f0 * df[4]  + uf0 * df[5];
                        float f2 = a2f1 * df[6] + a1f1 * df[7]  + uf1 * df[8];
                        float f3 = a2f1 * df[9] + a1f1 * df[10] + uf1 * df[11];
                        float g0 = a2g0 * dg[0] + a1g0 * dg[1]  + ug0 * dg[2];
                        float g1 = a2g0 * dg[3] + a1g0 * dg[4]  + ug0 * dg[5];
                        float g2 = a2g1 * dg[6] + a1g1 * dg[7]  + ug1 * dg[8];
                        float g3 = a2g1 * dg[9] + a1g1 * dg[10] + ug1 * dg[11];
                        bwv[mtf][nt][2 * rp] =
                            packh2(fast_tanh(f0) * fast_sig(g0), fast_tanh(f1) * fast_sig(g1));
                        bwv[mtf][nt][2 * rp + 1] =
                            packh2(fast_tanh(f2) * fast_sig(g2), fast_tanh(f3) * fast_sig(g3));
                    }
                }
            }
        }

        // ---------- s-GEMM + sLast + z-update (LDS bounce) + stats ----------
        float s1 = 0.f, s2 = 0.f;
        if (act) {
            uint4 Bw[2][4];
#pragma unroll
            for (int ks = 0; ks < 2; ks++)
#pragma unroll
                for (int nt = 0; nt < 4; nt++) {
                    uint4 v;
                    v.x = bwv[ks][nt][0]; v.y = bwv[ks][nt][1];
                    v.z = bwv[ks][nt][2]; v.w = bwv[ks][nt][3];
                    Bw[ks][nt] = v;
                }
            const uint4* AS = WPA + 8192 + (size_t)L * 16 * 64;
            unsigned* SB = scratch + wv * (16 * 66);   // wave-private bounce region
#pragma unroll
            for (int kt = 0; kt < 4; kt++) {
                f32x4 cs[2][4];
#pragma unroll
                for (int lo = 0; lo < 2; lo++) {
                    const int ms = 2 * kt + lo;
                    uint4 a0 = AS[(ms * 2 + 0) * 64 + lane];
                    uint4 a1 = AS[(ms * 2 + 1) * 64 + lane];
#pragma unroll
                    for (int nt = 0; nt < 4; nt++) {
                        f32x4 acc = {0.f, 0.f, 0.f, 0.f};
                        acc = mfma16(a0, Bw[0][nt], acc);
                        acc = mfma16(a1, Bw[1][nt], acc);
                        cs[lo][nt] = acc;
                    }
                }
                if (wv == 3 && cc == 15) {
#pragma unroll
                    for (int lo = 0; lo < 2; lo++)
#pragma unroll
                        for (int r = 0; r < 4; r++)
                            sLast[L * HC + 16 * (2 * kt + lo) + 4 * l4 + r] = cs[lo][3][r];
                }
                if (!lastL) {
                    // bounce write: rel chpair = 8lo+2l4+rp, col = 16nt+cc
#pragma unroll
                    for (int lo = 0; lo < 2; lo++)
#pragma unroll
                        for (int nt = 0; nt < 4; nt++) {
                            SB[(8 * lo + 2 * l4 + 0) * 66 + 16 * nt + cc] =
                                packh2(cs[lo][nt][0], cs[lo][nt][1]);
                            SB[(8 * lo + 2 * l4 + 1) * 66 + 16 * nt + cc] =
                                packh2(cs[lo][nt][2], cs[lo][nt][3]);
                        }
                    // bounce read in B-layout + GN update (intra-wave, DS ops in order)
#pragma unroll
                    for (int nt = 0; nt < 4; nt++) {
                        unsigned zp[4];
#pragma unroll
                        for (int q = 0; q < 4; q++) {
                            unsigned sp = SB[(4 * l4 + q) * 66 + 16 * nt + cc];
                            float sf0 = loh(sp), sf1 = hih(sp);
                            unsigned zold = u4get(zB[kt][nt], q);
                            float zo0 = loh(zold), zo1 = hih(zold);
                            float2 gv = *(const float2*)(Gp + L * HC + 32 * kt + 8 * l4 + 2 * q);
                            float2 bv = *(const float2*)(Bp + L * HC + 32 * kt + 8 * l4 + 2 * q);
                            float zn0 = fmaf(zo0, r_s * gv.x, (bv.x - mr * gv.x) + sf0);
                            float zn1 = fmaf(zo1, r_s * gv.y, (bv.y - mr * gv.y) + sf1);
                            zp[q] = packh2(zn0, zn1);
                            s1 += zn0 + zn1;
                            s2 += zn0 * zn0 + zn1 * zn1;
                        }
                        uint4 v;
                        v.x = zp[0]; v.y = zp[1]; v.z = zp[2]; v.w = zp[3];
                        zB[kt][nt] = v;
                    }
                }
            }
        }
        if (!lastL) {
#pragma unroll
            for (int off = 32; off; off >>= 1) {
                s1 += __shfl_xor(s1, off);
                s2 += __shfl_xor(s2, off);
            }
            if (lane == 0) { red[wv * 2] = s1; red[wv * 2 + 1] = s2; }
            __syncthreads();   // B2
            float S1 = red[0] + red[2] + red[4] + red[6];
            float S2 = red[1] + red[3] + red[5] + red[7];
            float mu = S1 * (1.f / 32768.f);
            float var = S2 * (1.f / 32768.f) - mu * mu;
            m_s = mu;
            r_s = rsqrtf(var + 1e-5f);
        }
    }
    __syncthreads();   // sLast complete; scratch free for head bufs

    // ---------- head: h_last = sum_i skip_w[i] @ sLast[i]; LN; MLP ----------
    float hl = 0.f;
    if (t < HC) {
        for (int i = 0; i < NL; i++) {
            const float4* swr = (const float4*)(skip_w + (((size_t)i * HC) + t) * HC);
            const float* sl = sLast + i * HC;
#pragma unroll 4
            for (int c4 = 0; c4 < 32; c4++) {
                float4 sw = swr[c4];
                hl += sw.x * sl[4 * c4] + sw.y * sl[4 * c4 + 1] + sw.z * sl[4 * c4 + 2] + sw.w * sl[4 * c4 + 3];
            }
        }
        hbuf[t] = hl;
    }
    __syncthreads();
    if (t < 64) {
        float v0 = hbuf[t], v1 = hbuf[t + 64];
        float a = v0 + v1, q = v0 * v0 + v1 * v1;
#pragma unroll
        for (int off = 32; off; off >>= 1) {
            a += __shfl_xor(a, off);
            q += __shfl_xor(q, off);
        }
        if (t == 0) {
            float mu = a * (1.f / 128.f);
            red[0] = mu;
            red[1] = rsqrtf(q * (1.f / 128.f) - mu * mu + 1e-5f);
        }
    }
    __syncthreads();
    {
        float mu = red[0], rs = red[1];
        if (t < HC) hbuf[t] = (hl - mu) * rs * ln_g[t] + ln_b[t];
    }
    __syncthreads();
    if (t < HC) {
        float q = h1_b[t];
        for (int c = 0; c < HC; c++) q = fmaf(hbuf[c], h1_w[c * HC + t], q);
        q = 0.5f * q * (1.f + erff(q * 0.70710678118654752f));
        qbuf[t] = q;
    }
    __syncthreads();
    if (t < 24) {
        float o = h2_b[t];
        for (int c = 0; c < HC; c++) o = fmaf(qbuf[c], h2_w[c * 24 + t], o);
        out[((size_t)b * 24 + t) * 128 + n] = o;
    }
}

extern "C" void kernel_launch(void* const* d_in, const int* in_sizes, int n_in,
                              void* d_out, int out_size, void* d_ws, size_t ws_size,
                              hipStream_t stream) {
    const float* x      = (const float*)d_in[0];
    const float* in_w   = (const float*)d_in[1];
    const float* in_b   = (const float*)d_in[2];
    const float* pw_in  = (const float*)d_in[3];
    const float* dw_w   = (const float*)d_in[4];
    const float* pw_out = (const float*)d_in[5];
    const float* gn_g   = (const float*)d_in[6];
    const float* gn_b   = (const float*)d_in[7];
    const float* skip_w = (const float*)d_in[8];
    const float* ln_g   = (const float*)d_in[9];
    const float* ln_b   = (const float*)d_in[10];
    const float* h1_w   = (const float*)d_in[11];
    const float* h1_b   = (const float*)d_in[12];
    const float* h2_w   = (const float*)d_in[13];
    const float* h2_b   = (const float*)d_in[14];
    float* out = (float*)d_out;
    float* ws  = (float*)d_ws;

    tcn_setup<<<NL, 256, 0, stream>>>(pw_in, pw_out, gn_g, gn_b, ws);

    tcn_main<<<1024, 256, 0, stream>>>(x, in_w, in_b, dw_w, pw_out, skip_w,
                                       ln_g, ln_b, h1_w, h1_b, h2_w, h2_b, ws, out);
}